// Round 16
// baseline (146.505 us; speedup 1.0000x reference)
//
#include <hip/hip_runtime.h>
#include <stdint.h>

#define H_ 152
#define W_ 152
#define A_ 9
#define HW_ (H_ * W_)          // 23104
#define N_ (HW_ * A_)          // 207936
#define B_ 8
#define PRE_TOP 6000
#define POST_TOP 300
#define NBUCK 4096
#define NFINE 32768
#define CAND_CAP 8192
#define NMS_TH 0.7f
#define CNT_STRIDE 32          // pad per-batch counters to 128 B

// workspace byte offsets
#define OFF_HIST    0                                   // 8*4096*4 = 131072
#define OFF_CNT     262144                              // 8*32*4 = 1024 (+done[8]@240, bucketT[8]@248)
#define OFF_BOXES   1311744                             // 8*6000*16= 768000
#define OFF_CANDBOX 2079744                             // 8*8192*16 = 1048576
#define OFF_CAND    263168                              // 8*8192*8 = 524288
#define WS_NEED     (2079744ull + 1048576ull)           // 3128320

// ---------- helpers ----------

__device__ __forceinline__ unsigned fkey(float f) {
    unsigned u = __float_as_uint(f);
    return (u & 0x80000000u) ? ~u : (u | 0x80000000u);   // monotonic float->u32
}

__device__ __forceinline__ bool sup_test(float ax1, float ay1, float ax2, float ay2, float aar,
                                         float bx1, float by1, float bx2, float by2, float bar) {
    float xx1 = fmaxf(ax1, bx1);
    float yy1 = fmaxf(ay1, by1);
    float xx2 = fminf(ax2, bx2);
    float yy2 = fminf(ay2, by2);
    float iw = fmaxf(xx2 - xx1 + 1.0f, 0.0f);
    float ih = fmaxf(yy2 - yy1 + 1.0f, 0.0f);
    float inter = __fmul_rn(iw, ih);
    float iou = inter / (aar + bar - inter);
    return iou > NMS_TH;
}

// decode one box, op-order identical to reference/numpy
__device__ __forceinline__ float4 decode_box(float an0, float an1, float an2, float an3,
                                             float sx, float sy,
                                             float dx, float dy, float dw, float dh,
                                             float wmax, float hmax) {
    float ax1 = an0 + sx;
    float ay1 = an1 + sy;
    float ax2 = an2 + sx;
    float ay2 = an3 + sy;
    float ww = ax2 - ax1 + 1.0f;
    float hh = ay2 - ay1 + 1.0f;
    float ctx = ax1 + 0.5f * ww;
    float cty = ay1 + 0.5f * hh;
    float pcx = __fadd_rn(__fmul_rn(dx, ww), ctx);   // no FMA contraction (match np)
    float pcy = __fadd_rn(__fmul_rn(dy, hh), cty);
    float pw = __fmul_rn(expf(dw), ww);
    float ph = __fmul_rn(expf(dh), hh);
    float x1 = pcx - 0.5f * pw;
    float y1 = pcy - 0.5f * ph;
    float x2 = pcx + 0.5f * pw;
    float y2 = pcy + 0.5f * ph;
    x1 = fminf(fmaxf(x1, 0.0f), wmax);
    y1 = fminf(fmaxf(y1, 0.0f), hmax);
    x2 = fminf(fmaxf(x2, 0.0f), wmax);
    y2 = fminf(fmaxf(y2, 0.0f), hmax);
    return make_float4(x1, y1, x2, y2);
}

// ---------- kernels ----------

// zero hist (32768 words) + cnt region (256 words, incl. done + bucketT slots)
__global__ void zero_k(unsigned* __restrict__ ws) {
    unsigned* cntr = (unsigned*)((char*)ws + OFF_CNT);
    int i = blockIdx.x * blockDim.x + threadIdx.x;
    int st = gridDim.x * blockDim.x;
    for (int k = i; k < 32768 + 256; k += st) {
        if (k < 32768) ws[k] = 0u;
        else cntr[k - 32768] = 0u;
    }
}

// histogram + (last block per batch) suffix scan to find the coarse threshold bucket
__global__ void hist_scan_k(const float* __restrict__ scores, unsigned* __restrict__ hist,
                            unsigned* __restrict__ done, unsigned* __restrict__ bucketT) {
    __shared__ unsigned lh[NBUCK];
    __shared__ unsigned ps[256];
    __shared__ int s_last;
    int b = blockIdx.y, t = threadIdx.x;
    for (int i = t; i < NBUCK; i += blockDim.x) lh[i] = 0;
    __syncthreads();
    const float4* sb = (const float4*)(scores + ((size_t)b * 18 + A_) * HW_);
    const int N4 = N_ / 4;                      // 51984
    int stride = gridDim.x * blockDim.x;
    for (int e = blockIdx.x * blockDim.x + t; e < N4; e += stride) {
        float4 v = sb[e];
        atomicAdd(&lh[fkey(v.x) >> 20], 1u);
        atomicAdd(&lh[fkey(v.y) >> 20], 1u);
        atomicAdd(&lh[fkey(v.z) >> 20], 1u);
        atomicAdd(&lh[fkey(v.w) >> 20], 1u);
    }
    __syncthreads();
    unsigned* hb = hist + b * NBUCK;
    for (int i = t; i < NBUCK; i += blockDim.x) {
        unsigned v = lh[i];
        if (v) atomicAdd(&hb[i], v);
    }
    __syncthreads();
    __threadfence();
    if (t == 0) s_last = (atomicAdd(&done[b], 1u) == (unsigned)(gridDim.x - 1));
    __syncthreads();
    if (!s_last) return;

    // last block: suffix scan (256 threads x 16 buckets, descending f)
    unsigned c[16];
    unsigned local = 0;
#pragma unroll
    for (int k = 0; k < 16; ++k) {
        int f = 4095 - (16 * t + k);
        c[k] = __hip_atomic_load(&hb[f], __ATOMIC_RELAXED, __HIP_MEMORY_SCOPE_AGENT);
        local += c[k];
    }
    ps[t] = local;
    __syncthreads();
    for (int off = 1; off < 256; off <<= 1) {
        unsigned v = (t >= off) ? ps[t - off] : 0u;
        __syncthreads();
        ps[t] += v;
        __syncthreads();
    }
    unsigned incl = ps[t], excl = incl - local;
    if (excl < PRE_TOP && incl >= PRE_TOP) {
        unsigned cum = excl;
#pragma unroll
        for (int k = 0; k < 16; ++k) {
            cum += c[k];
            if (cum >= PRE_TOP) { bucketT[b] = (unsigned)(4095 - (16 * t + k)); break; }
        }
    }
    if (t == 255 && ps[255] < PRE_TOP) bucketT[b] = 0;  // safety: include everything
}

// compact + inline decode: candidates write (key,n) to cand[o] AND decoded box to candbox[o]
__global__ void compact_k(const float* __restrict__ scores, const float* __restrict__ deltas,
                          const float* __restrict__ anchors, const float* __restrict__ im_info,
                          const unsigned* __restrict__ bucketT,
                          unsigned* __restrict__ cnt, uint2* __restrict__ cand,
                          float4* __restrict__ candbox) {
    __shared__ unsigned wtot[4], wbase[4];
    __shared__ unsigned blkbase;
    int b = blockIdx.y;
    const float4* sb = (const float4*)(scores + ((size_t)b * 18 + A_) * HW_);
    const float* db = deltas + (size_t)b * 36 * HW_;
    float hmax = im_info[b * 3 + 0] - 1.0f;
    float wmax = im_info[b * 3 + 1] - 1.0f;
    unsigned T = bucketT[b];
    int lane = threadIdx.x & 63;
    int wid = threadIdx.x >> 6;
    const int N4 = N_ / 4;
    int stride = gridDim.x * blockDim.x;
    int niters = (N4 + stride - 1) / stride;
    unsigned long long lower = (lane == 63) ? 0x7fffffffffffffffull
                                            : ((1ull << lane) - 1ull);
    uint2* cb = cand + (size_t)b * CAND_CAP;
    float4* cx = candbox + (size_t)b * CAND_CAP;
    for (int it = 0; it < niters; ++it) {
        int e = it * stride + blockIdx.x * (int)blockDim.x + (int)threadIdx.x;
        bool p0 = false, p1 = false, p2 = false, p3 = false;
        unsigned k0 = 0, k1 = 0, k2 = 0, k3 = 0;
        if (e < N4) {
            float4 v = sb[e];
            k0 = fkey(v.x); k1 = fkey(v.y); k2 = fkey(v.z); k3 = fkey(v.w);
            p0 = (k0 >> 20) >= T; p1 = (k1 >> 20) >= T;
            p2 = (k2 >> 20) >= T; p3 = (k3 >> 20) >= T;
        }
        unsigned long long m0 = __ballot(p0), m1 = __ballot(p1);
        unsigned long long m2 = __ballot(p2), m3 = __ballot(p3);
        unsigned t0 = (unsigned)__popcll(m0), t1 = (unsigned)__popcll(m1);
        unsigned t2 = (unsigned)__popcll(m2), t3 = (unsigned)__popcll(m3);
        unsigned wtotal = t0 + t1 + t2 + t3;
        if (lane == 0) wtot[wid] = wtotal;
        __syncthreads();
        if (threadIdx.x == 0) {
            unsigned s0 = wtot[0], s1 = wtot[1], s2 = wtot[2], s3 = wtot[3];
            unsigned tot = s0 + s1 + s2 + s3;
            blkbase = tot ? atomicAdd(&cnt[b * CNT_STRIDE], tot) : 0u;
            wbase[0] = 0; wbase[1] = s0; wbase[2] = s0 + s1; wbase[3] = s0 + s1 + s2;
        }
        __syncthreads();
        if (wtotal) {
            unsigned base = blkbase + wbase[wid];
            unsigned o0 = base + (unsigned)__popcll(m0 & lower);
            unsigned o1 = base + t0 + (unsigned)__popcll(m1 & lower);
            unsigned o2 = base + t0 + t1 + (unsigned)__popcll(m2 & lower);
            unsigned o3 = base + t0 + t1 + t2 + (unsigned)__popcll(m3 & lower);
            int e4 = e * 4;
#define EMIT(P, O, K, IDX)                                                      \
            if (P && O < CAND_CAP) {                                            \
                int a = (IDX) / HW_, pix = (IDX) - a * HW_;                     \
                cb[O] = make_uint2(K, (unsigned)(pix * A_ + a));                \
                int didx = (4 * a) * HW_ + pix;                                 \
                float dx = db[didx];                                            \
                float dy = db[didx + HW_];                                      \
                float dw = db[didx + 2 * HW_];                                  \
                float dh = db[didx + 3 * HW_];                                  \
                int w = pix % W_, h = pix / W_;                                 \
                cx[O] = decode_box(anchors[a * 4 + 0], anchors[a * 4 + 1],      \
                                   anchors[a * 4 + 2], anchors[a * 4 + 3],      \
                                   (float)(w * 16), (float)(h * 16),            \
                                   dx, dy, dw, dh, wmax, hmax);                 \
            }
            EMIT(p0, o0, k0, e4 + 0)
            EMIT(p1, o1, k1, e4 + 1)
            EMIT(p2, o2, k2, e4 + 2)
            EMIT(p3, o3, k3, e4 + 3)
#undef EMIT
        }
    }
}

// Fused fine counting-sort + rank, fully LDS-resident (1 block/batch).
// Counts as packed u16 pairs; composite = key[63:32] | (~n&0x3FFFF)[31:14] | slot[13:0].
__global__ void __launch_bounds__(1024) sortrank_k(const unsigned* __restrict__ cnt,
                                                   const uint2* __restrict__ cand,
                                                   const float4* __restrict__ candbox,
                                                   float4* __restrict__ boxes) {
    __shared__ unsigned lh32[NFINE / 2];          // 64 KiB: two u16 counters per word
    __shared__ unsigned long long gl[CAND_CAP];   // 64 KiB
    __shared__ unsigned ps[1024];                 // 4 KiB
    int b = blockIdx.x, t = threadIdx.x;
    int M = min((int)cnt[b * CNT_STRIDE], CAND_CAP);
    const uint2* cb = cand + (size_t)b * CAND_CAP;
    for (int i = t; i < NFINE / 2; i += 1024) lh32[i] = 0u;
    __syncthreads();
    // count
    for (int i = t; i < M; i += 1024) {
        unsigned key16 = cb[i].x >> 16;
        unsigned f = (key16 >= 32768u) ? (key16 - 32768u) : 0u;
        atomicAdd(&lh32[f & 16383u], 1u << (16u * (f >> 14)));
    }
    __syncthreads();
    // per-thread 32-bucket gather (descending f; stride aligns halves cleanly)
    unsigned c[32];
    unsigned local = 0;
#pragma unroll
    for (int k = 0; k < 32; ++k) {
        unsigned f = 32767u - (32u * t + k);
        c[k] = (lh32[f & 16383u] >> (16u * (f >> 14))) & 0xFFFFu;
        local += c[k];
    }
    ps[t] = local;
    __syncthreads();
    for (int off = 1; off < 1024; off <<= 1) {
        unsigned v = (t >= off) ? ps[t - off] : 0u;
        __syncthreads();
        ps[t] += v;
        __syncthreads();
    }
    unsigned run = ps[t] - local;
    __syncthreads();
    for (int i = t; i < NFINE / 2; i += 1024) lh32[i] = 0u;
    __syncthreads();
#pragma unroll
    for (int k = 0; k < 32; ++k) {      // write packed S_start
        unsigned f = 32767u - (32u * t + k);
        if (run) atomicOr(&lh32[f & 16383u], (run & 0xFFFFu) << (16u * (f >> 14)));
        run += c[k];
    }
    __syncthreads();
    // scatter into gl (bucket-sorted); after this, lh32 holds packed END offsets
    for (int i = t; i < M; i += 1024) {
        uint2 cd = cb[i];
        unsigned key16 = cd.x >> 16;
        unsigned f = (key16 >= 32768u) ? (key16 - 32768u) : 0u;
        unsigned sh = 16u * (f >> 14);
        unsigned old = atomicAdd(&lh32[f & 16383u], 1u << sh);
        unsigned pos = (old >> sh) & 0xFFFFu;
        if (pos < CAND_CAP)
            gl[pos] = ((unsigned long long)cd.x << 32) |
                      ((unsigned long long)((~cd.y) & 0x3FFFFu) << 14) |
                      (unsigned long long)i;
    }
    __syncthreads();
    // rank within fine bucket; emit pre-decoded box to boxes[b][rank]
    const float4* cx = candbox + (size_t)b * CAND_CAP;
    for (int i = t; i < M; i += 1024) {
        unsigned long long comp = gl[i];
        unsigned key16 = (unsigned)(comp >> 48);
        int f = (key16 >= 32768u) ? (int)(key16 - 32768u) : 0;
        unsigned shf = 16u * ((unsigned)f >> 14);
        int be = (int)((lh32[(unsigned)f & 16383u] >> shf) & 0xFFFFu);
        int bs = 0;
        if (f < 32767) {
            int f1 = f + 1;
            unsigned sh1 = 16u * ((unsigned)f1 >> 14);
            bs = (int)((lh32[(unsigned)f1 & 16383u] >> sh1) & 0xFFFFu);
        }
        be = min(be, M); bs = min(bs, M);
        int cgt = 0, j = bs;
        int a0 = 0, a1 = 0, a2 = 0, a3 = 0;
        for (; j + 4 <= be; j += 4) {
            a0 += (gl[j + 0] > comp);
            a1 += (gl[j + 1] > comp);
            a2 += (gl[j + 2] > comp);
            a3 += (gl[j + 3] > comp);
        }
        for (; j < be; ++j) cgt += (gl[j] > comp);
        cgt += a0 + a1 + a2 + a3;
        int rank = bs + cgt;
        if (rank < PRE_TOP) {
            unsigned slot = (unsigned)(comp & 0x3FFFull);
            boxes[(size_t)b * PRE_TOP + rank] = cx[slot];
        }
    }
}

// NMS: R12 measured-best (4 barriers, t0-serial walk, append phase),
// float4-packed LDS, hoisted lane-own box, ballot-aggregated intra atomics.
__global__ void __launch_bounds__(1024) nms_k(const float4* __restrict__ boxes,
                                              float* __restrict__ out) {
    __shared__ float4 kbox[POST_TOP];
    __shared__ float  karea[POST_TOP];
    __shared__ float4 gbox4[64];
    __shared__ float  gar[64];
    __shared__ unsigned extw[2];
    __shared__ unsigned intraw[128];   // row jj: bits ll that jj suppresses
    __shared__ unsigned long long s_keep;
    __shared__ int s_base, s_kc, s_done;
    int b = blockIdx.x, t = threadIdx.x;
    int lane = t & 63, w = t >> 6;
    if (t == 0) { s_kc = 0; s_done = 0; }
    const float4* bb = boxes + (size_t)b * PRE_TOP;
    const int ngroups = (PRE_TOP + 63) / 64;   // 94

    float4 vcur = make_float4(0.f, 0.f, 0.f, 0.f);
    if (t < 64) vcur = bb[t];                 // prefetch group 0

    for (int g = 0; g < ngroups; ++g) {
        __syncthreads();                       // prev append + s_kc visible
        if (s_done) break;
        int gbase = g * 64;
        int gsz = min(64, PRE_TOP - gbase);
        if (t < gsz) {
            gbox4[t] = vcur;
            gar[t] = __fmul_rn(vcur.z - vcur.x + 1.0f, vcur.w - vcur.y + 1.0f);
        }
        if (t < 64) {                          // prefetch next group under this compute
            int nidx = min(gbase + 64 + t, PRE_TOP - 1);
            vcur = bb[nidx];
        }
        if (t < 2) extw[t] = 0u;
        if (t < 128) intraw[t] = 0u;
        __syncthreads();

        int kc = s_kc;
        // ext phase: 16 threads per candidate vs kept list (packed reads: 2 LDS/iter)
        {
            int j = t >> 4, sub = t & 15;
            if (j < gsz) {
                float4 cb4 = gbox4[j];          // 16-lane broadcast
                float car = gar[j];
                bool any = false;
                for (int kk = sub; kk < kc && !any; kk += 16) {
                    float4 kb = kbox[kk];
                    float ka = karea[kk];
                    any = sup_test(kb.x, kb.y, kb.z, kb.w, ka,
                                   cb4.x, cb4.y, cb4.z, cb4.w, car);
                }
                if (any) atomicOr(&extw[j >> 5], 1u << (j & 31));
            }
        }
        // intra phase: lane = ll (own box in regs); wave w covers jj in
        // {w, w+16, w+32, w+48} (wave-uniform broadcast); ballot-aggregated write.
        {
            float4 mb = gbox4[lane];            // stride-1 b128, conflict-free
            float mar = gar[lane];
#pragma unroll
            for (int it = 0; it < 4; ++it) {
                int jj = w + it * 16;
                float4 bj = gbox4[jj];          // wave-uniform broadcast
                float baj = gar[jj];
                bool sup = (jj < lane) && (lane < gsz) && (jj < gsz) &&
                           sup_test(bj.x, bj.y, bj.z, bj.w, baj,
                                    mb.x, mb.y, mb.z, mb.w, mar);
                unsigned long long m = __ballot(sup);
                if (lane == 0 && (unsigned)m) atomicOr(&intraw[2 * jj], (unsigned)m);
                if (lane == 1 && (unsigned)(m >> 32))
                    atomicOr(&intraw[2 * jj + 1], (unsigned)(m >> 32));
            }
        }
        __syncthreads();

        if (t == 0) {
            unsigned long long ext64 = (unsigned long long)extw[0] |
                                       ((unsigned long long)extw[1] << 32);
            unsigned long long validm = (gsz >= 64) ? ~0ull : ((1ull << gsz) - 1ull);
            unsigned long long alive = (~ext64) & validm;
            unsigned long long keep = 0ull;
            int kcc = s_kc;
            s_base = kcc;
            while (alive && kcc < POST_TOP) {
                int j = __ffsll((long long)alive) - 1;
                keep |= (1ull << j);
                ++kcc;
                unsigned long long row = (unsigned long long)intraw[2 * j] |
                                         ((unsigned long long)intraw[2 * j + 1] << 32);
                alive &= ~row;
                alive &= ~(1ull << j);
            }
            s_keep = keep;
            s_kc = kcc;
            if (kcc >= POST_TOP) s_done = 1;
        }
        __syncthreads();

        if (t < gsz && ((s_keep >> t) & 1ull)) {
            int rank = __popcll(s_keep & ((1ull << t) - 1ull));
            int slot = s_base + rank;
            float4 mb = gbox4[t];
            kbox[slot] = mb;
            karea[slot] = gar[t];
            float* o = out + (size_t)(b * POST_TOP + slot) * 5;
            o[0] = (float)b; o[1] = mb.x; o[2] = mb.y; o[3] = mb.z; o[4] = mb.w;
        }
    }
    __syncthreads();
    for (int sl = s_kc + t; sl < POST_TOP; sl += 1024) {
        float* o = out + (size_t)(b * POST_TOP + sl) * 5;
        o[0] = (float)b; o[1] = 0.f; o[2] = 0.f; o[3] = 0.f; o[4] = 0.f;
    }
}

// ---------- launch ----------

extern "C" void kernel_launch(void* const* d_in, const int* in_sizes, int n_in,
                              void* d_out, int out_size, void* d_ws, size_t ws_size,
                              hipStream_t stream) {
    const float* scores  = (const float*)d_in[0];   // (8, 18, 152, 152)
    const float* deltas  = (const float*)d_in[1];   // (8, 36, 152, 152)
    const float* im_info = (const float*)d_in[2];   // (8, 3)
    const float* anchors = (const float*)d_in[3];   // (9, 4)
    float* out = (float*)d_out;                     // (8, 300, 5)

    unsigned* hist    = (unsigned*)((char*)d_ws + OFF_HIST);
    unsigned* cnt     = (unsigned*)((char*)d_ws + OFF_CNT);
    uint2*    cand    = (uint2*)((char*)d_ws + OFF_CAND);
    float4*   boxes   = (float4*)((char*)d_ws + OFF_BOXES);
    float4*   candbox = (float4*)((char*)d_ws + OFF_CANDBOX);
    unsigned* done    = cnt + 240;                  // free slots in the zeroed cnt region
    unsigned* bucketT = cnt + 248;

    zero_k<<<32, 256, 0, stream>>>((unsigned*)d_ws);
    hist_scan_k<<<dim3(64, B_), 256, 0, stream>>>(scores, hist, done, bucketT);
    compact_k<<<dim3(64, B_), 256, 0, stream>>>(scores, deltas, anchors, im_info,
                                                bucketT, cnt, cand, candbox);
    sortrank_k<<<B_, 1024, 0, stream>>>(cnt, cand, candbox, boxes);
    nms_k<<<B_, 1024, 0, stream>>>(boxes, out);
}

// Round 17
// 121.296 us; speedup vs baseline: 1.2078x; 1.2078x over previous
//
#include <hip/hip_runtime.h>
#include <stdint.h>

#define H_ 152
#define W_ 152
#define A_ 9
#define HW_ (H_ * W_)          // 23104
#define N_ (HW_ * A_)          // 207936
#define B_ 8
#define PRE_TOP 6000
#define POST_TOP 300
#define NBUCK 4096
#define NFINE 32768
#define CAND_CAP 8192
#define NMS_TH 0.7f
#define CNT_STRIDE 32          // pad per-batch counters to 128 B
#define RTILE 512
#define DEC_PIXBLK 91          // ceil(23104/256)
#define DEC_BLKS (72 * DEC_PIXBLK)   // 6552
#define ZERO_BLKS 128

// workspace byte offsets
#define OFF_HIST    0                                   // 8*4096*4 = 131072 (reused: slot16 after scan — unused here)
#define OFF_SSUF    131072                              // (unused, kept for layout)
#define OFF_CNT     262144                              // 8*32*4 = 1024 (+done@240, bucketT@248)
#define OFF_CAND    263168                              // 8*8192*8 = 524288  (reused as S16 u16[32768]/batch)
#define OFF_GROUP   787456                              // 8*8192*8 = 524288
#define OFF_BOXES   1311744                             // 8*6000*16= 768000
#define OFF_BALL    2079744                             // 8*207936*16 = 26615808
#define WS_NEED     (2079744ull + 26615808ull)          // 28695552

// ---------- helpers ----------

__device__ __forceinline__ unsigned fkey(float f) {
    unsigned u = __float_as_uint(f);
    return (u & 0x80000000u) ? ~u : (u | 0x80000000u);   // monotonic float->u32
}

__device__ __forceinline__ bool sup_test(float ax1, float ay1, float ax2, float ay2, float aar,
                                         float bx1, float by1, float bx2, float by2, float bar) {
    float xx1 = fmaxf(ax1, bx1);
    float yy1 = fmaxf(ay1, by1);
    float xx2 = fminf(ax2, bx2);
    float yy2 = fminf(ay2, by2);
    float iw = fmaxf(xx2 - xx1 + 1.0f, 0.0f);
    float ih = fmaxf(yy2 - yy1 + 1.0f, 0.0f);
    float inter = __fmul_rn(iw, ih);
    float iou = inter / (aar + bar - inter);
    return iou > NMS_TH;
}

// decode one box, op-order identical to reference/numpy
__device__ __forceinline__ float4 decode_box(float an0, float an1, float an2, float an3,
                                             float sx, float sy,
                                             float dx, float dy, float dw, float dh,
                                             float wmax, float hmax) {
    float ax1 = an0 + sx;
    float ay1 = an1 + sy;
    float ax2 = an2 + sx;
    float ay2 = an3 + sy;
    float ww = ax2 - ax1 + 1.0f;
    float hh = ay2 - ay1 + 1.0f;
    float ctx = ax1 + 0.5f * ww;
    float cty = ay1 + 0.5f * hh;
    float pcx = __fadd_rn(__fmul_rn(dx, ww), ctx);   // no FMA contraction (match np)
    float pcy = __fadd_rn(__fmul_rn(dy, hh), cty);
    float pw = __fmul_rn(expf(dw), ww);
    float ph = __fmul_rn(expf(dh), hh);
    float x1 = pcx - 0.5f * pw;
    float y1 = pcy - 0.5f * ph;
    float x2 = pcx + 0.5f * pw;
    float y2 = pcy + 0.5f * ph;
    x1 = fminf(fmaxf(x1, 0.0f), wmax);
    y1 = fminf(fmaxf(y1, 0.0f), hmax);
    x2 = fminf(fmaxf(x2, 0.0f), wmax);
    y2 = fminf(fmaxf(y2, 0.0f), hmax);
    return make_float4(x1, y1, x2, y2);
}

// ---------- kernels ----------

// fused: decode all boxes (blocks 0..DEC_BLKS-1) + zero scratch (last ZERO_BLKS blocks)
__global__ void init_k(const float* __restrict__ deltas,
                       const float* __restrict__ anchors,
                       const float* __restrict__ im_info,
                       float4* __restrict__ ball,
                       unsigned* __restrict__ zbase, unsigned* __restrict__ zboxes,
                       int nDecBlks) {
    int bid = blockIdx.x;
    if (bid < nDecBlks) {
        int ba = bid / DEC_PIXBLK;
        int b = ba / A_, a = ba - (ba / A_) * A_;
        int pix = (bid % DEC_PIXBLK) * 256 + threadIdx.x;
        if (pix >= HW_) return;
        const float* db = deltas + ((size_t)b * 36 + 4 * a) * HW_;
        float dx = db[pix];
        float dy = db[pix + HW_];
        float dw = db[pix + 2 * HW_];
        float dh = db[pix + 3 * HW_];
        float an0 = anchors[a * 4 + 0];
        float an1 = anchors[a * 4 + 1];
        float an2 = anchors[a * 4 + 2];
        float an3 = anchors[a * 4 + 3];
        float hmax = im_info[b * 3 + 0] - 1.0f;
        float wmax = im_info[b * 3 + 1] - 1.0f;
        int w = pix % W_, h = pix / W_;
        float sx = (float)(w * 16), sy = (float)(h * 16);
        ball[(size_t)b * N_ + a * HW_ + pix] =
            decode_box(an0, an1, an2, an3, sx, sy, dx, dy, dw, dh, wmax, hmax);
    } else {
        const int n1 = 263168 / 4;      // hist + (ssuf pad) + cnt(incl. done/bucketT)
        const int n2 = 768000 / 4;      // boxes (defensive)
        int i = (bid - nDecBlks) * 256 + (int)threadIdx.x;
        int st = ZERO_BLKS * 256;
        for (int k = i; k < n1 + n2; k += st) {
            if (k < n1) zbase[k] = 0u;
            else zboxes[k - n1] = 0u;
        }
    }
}

// histogram + (last block per batch) suffix scan to find the coarse threshold bucket
__global__ void hist_scan_k(const float* __restrict__ scores, unsigned* __restrict__ hist,
                            unsigned* __restrict__ done, unsigned* __restrict__ bucketT) {
    __shared__ unsigned lh[NBUCK];
    __shared__ unsigned ps[256];
    __shared__ int s_last;
    int b = blockIdx.y, t = threadIdx.x;
    for (int i = t; i < NBUCK; i += blockDim.x) lh[i] = 0;
    __syncthreads();
    const float4* sb = (const float4*)(scores + ((size_t)b * 18 + A_) * HW_);
    const int N4 = N_ / 4;                      // 51984
    int stride = gridDim.x * blockDim.x;
    for (int e = blockIdx.x * blockDim.x + t; e < N4; e += stride) {
        float4 v = sb[e];
        atomicAdd(&lh[fkey(v.x) >> 20], 1u);
        atomicAdd(&lh[fkey(v.y) >> 20], 1u);
        atomicAdd(&lh[fkey(v.z) >> 20], 1u);
        atomicAdd(&lh[fkey(v.w) >> 20], 1u);
    }
    __syncthreads();
    unsigned* hb = hist + b * NBUCK;
    for (int i = t; i < NBUCK; i += blockDim.x) {
        unsigned v = lh[i];
        if (v) atomicAdd(&hb[i], v);
    }
    __syncthreads();
    __threadfence();
    if (t == 0) s_last = (atomicAdd(&done[b], 1u) == (unsigned)(gridDim.x - 1));
    __syncthreads();
    if (!s_last) return;

    // last block: suffix scan (256 threads x 16 buckets, descending f)
    unsigned c[16];
    unsigned local = 0;
#pragma unroll
    for (int k = 0; k < 16; ++k) {
        int f = 4095 - (16 * t + k);
        c[k] = __hip_atomic_load(&hb[f], __ATOMIC_RELAXED, __HIP_MEMORY_SCOPE_AGENT);
        local += c[k];
    }
    ps[t] = local;
    __syncthreads();
    for (int off = 1; off < 256; off <<= 1) {
        unsigned v = (t >= off) ? ps[t - off] : 0u;
        __syncthreads();
        ps[t] += v;
        __syncthreads();
    }
    unsigned incl = ps[t], excl = incl - local;
    if (excl < PRE_TOP && incl >= PRE_TOP) {
        unsigned cum = excl;
#pragma unroll
        for (int k = 0; k < 16; ++k) {
            cum += c[k];
            if (cum >= PRE_TOP) { bucketT[b] = (unsigned)(4095 - (16 * t + k)); break; }
        }
    }
    if (t == 255 && ps[255] < PRE_TOP) bucketT[b] = 0;  // safety: include everything
}

__global__ void compact_k(const float* __restrict__ scores, const unsigned* __restrict__ bucketT,
                          unsigned* __restrict__ cnt, uint2* __restrict__ cand) {
    __shared__ unsigned wtot[4], wbase[4];
    __shared__ unsigned blkbase;
    int b = blockIdx.y;
    const float4* sb = (const float4*)(scores + ((size_t)b * 18 + A_) * HW_);
    unsigned T = bucketT[b];
    int lane = threadIdx.x & 63;
    int wid = threadIdx.x >> 6;
    const int N4 = N_ / 4;
    int stride = gridDim.x * blockDim.x;
    int niters = (N4 + stride - 1) / stride;
    unsigned long long lower = (lane == 63) ? 0x7fffffffffffffffull
                                            : ((1ull << lane) - 1ull);
    for (int it = 0; it < niters; ++it) {
        int e = it * stride + blockIdx.x * (int)blockDim.x + (int)threadIdx.x;
        bool p0 = false, p1 = false, p2 = false, p3 = false;
        unsigned k0 = 0, k1 = 0, k2 = 0, k3 = 0;
        if (e < N4) {
            float4 v = sb[e];
            k0 = fkey(v.x); k1 = fkey(v.y); k2 = fkey(v.z); k3 = fkey(v.w);
            p0 = (k0 >> 20) >= T; p1 = (k1 >> 20) >= T;
            p2 = (k2 >> 20) >= T; p3 = (k3 >> 20) >= T;
        }
        unsigned long long m0 = __ballot(p0), m1 = __ballot(p1);
        unsigned long long m2 = __ballot(p2), m3 = __ballot(p3);
        unsigned t0 = (unsigned)__popcll(m0), t1 = (unsigned)__popcll(m1);
        unsigned t2 = (unsigned)__popcll(m2), t3 = (unsigned)__popcll(m3);
        unsigned wtotal = t0 + t1 + t2 + t3;
        if (lane == 0) wtot[wid] = wtotal;
        __syncthreads();
        if (threadIdx.x == 0) {
            unsigned s0 = wtot[0], s1 = wtot[1], s2 = wtot[2], s3 = wtot[3];
            unsigned tot = s0 + s1 + s2 + s3;
            blkbase = tot ? atomicAdd(&cnt[b * CNT_STRIDE], tot) : 0u;
            wbase[0] = 0; wbase[1] = s0; wbase[2] = s0 + s1; wbase[3] = s0 + s1 + s2;
        }
        __syncthreads();
        if (wtotal) {
            unsigned base = blkbase + wbase[wid];
            unsigned o0 = base + (unsigned)__popcll(m0 & lower);
            unsigned o1 = base + t0 + (unsigned)__popcll(m1 & lower);
            unsigned o2 = base + t0 + t1 + (unsigned)__popcll(m2 & lower);
            unsigned o3 = base + t0 + t1 + t2 + (unsigned)__popcll(m3 & lower);
            uint2* cb = cand + (size_t)b * CAND_CAP;
            int e4 = e * 4;
            if (p0 && o0 < CAND_CAP) {
                int a = (e4 + 0) / HW_, pix = (e4 + 0) - a * HW_;
                cb[o0] = make_uint2(k0, (unsigned)(pix * A_ + a));
            }
            if (p1 && o1 < CAND_CAP) {
                int a = (e4 + 1) / HW_, pix = (e4 + 1) - a * HW_;
                cb[o1] = make_uint2(k1, (unsigned)(pix * A_ + a));
            }
            if (p2 && o2 < CAND_CAP) {
                int a = (e4 + 2) / HW_, pix = (e4 + 2) - a * HW_;
                cb[o2] = make_uint2(k2, (unsigned)(pix * A_ + a));
            }
            if (p3 && o3 < CAND_CAP) {
                int a = (e4 + 3) / HW_, pix = (e4 + 3) - a * HW_;
                cb[o3] = make_uint2(k3, (unsigned)(pix * A_ + a));
            }
        }
    }
}

// Fine (16-bit) counting sort of candidates: histogram -> suffix scan -> scatter.
// Afterwards writes per-fine-bucket END offsets (u16) over the dead cand slice.
__global__ void __launch_bounds__(1024) finesort_k(const unsigned* __restrict__ cnt,
                                                   uint2* __restrict__ cand,
                                                   unsigned long long* __restrict__ grouped) {
    __shared__ unsigned lh[NFINE];     // 128 KiB
    __shared__ unsigned ps[1024];
    int b = blockIdx.x, t = threadIdx.x;
    int M = min((int)cnt[b * CNT_STRIDE], CAND_CAP);
    uint2* cb = cand + (size_t)b * CAND_CAP;
    unsigned long long* g = grouped + (size_t)b * CAND_CAP;
    for (int i = t; i < NFINE; i += 1024) lh[i] = 0u;
    __syncthreads();
    for (int i = t; i < M; i += 1024) {
        unsigned key16 = cb[i].x >> 16;
        unsigned f = (key16 >= 32768u) ? (key16 - 32768u) : 0u;
        atomicAdd(&lh[f], 1u);
    }
    __syncthreads();
    unsigned c[32];
    unsigned local = 0;
#pragma unroll
    for (int k = 0; k < 32; ++k) { c[k] = lh[32767 - (32 * t + k)]; local += c[k]; }
    ps[t] = local;
    __syncthreads();
    for (int off = 1; off < 1024; off <<= 1) {
        unsigned v = (t >= off) ? ps[t - off] : 0u;
        __syncthreads();
        ps[t] += v;
        __syncthreads();
    }
    unsigned run = ps[t] - local;       // elements in all higher-f chunks
    __syncthreads();
#pragma unroll
    for (int k = 0; k < 32; ++k) {      // overwrite lh with S_start[f]
        lh[32767 - (32 * t + k)] = run;
        run += c[k];
    }
    __syncthreads();
    for (int i = t; i < M; i += 1024) {
        uint2 cd = cb[i];
        unsigned key16 = cd.x >> 16;
        unsigned f = (key16 >= 32768u) ? (key16 - 32768u) : 0u;
        unsigned pos = atomicAdd(&lh[f], 1u);
        if (pos < CAND_CAP)
            g[pos] = ((unsigned long long)cd.x << 32) | (unsigned)(~cd.y);
    }
    __syncthreads();
    ushort* S16 = (ushort*)cb;          // cand slice is dead; 32768*2B = 64 KiB fits exactly
    for (int i = t; i < NFINE; i += 1024)
        S16[i] = (ushort)min(lh[i], 65535u);
}

// rank candidate within its FINE bucket (count greater composites), then place its
// (pre-decoded) box into boxes[b][rank].
__global__ void __launch_bounds__(256) rank_k(const unsigned* __restrict__ cnt,
                                              const unsigned long long* __restrict__ grouped,
                                              const ushort* __restrict__ S16all,
                                              const float4* __restrict__ ball,
                                              float4* __restrict__ boxes) {
    __shared__ unsigned long long tile[RTILE];
    __shared__ int s_rs, s_re;
    int b = blockIdx.y, t = threadIdx.x;
    int M = min((int)cnt[b * CNT_STRIDE], CAND_CAP);
    int c0 = blockIdx.x * 256;
    if (c0 >= M) return;
    const unsigned long long* g = grouped + (size_t)b * CAND_CAP;
    const ushort* S16 = S16all + (size_t)b * NFINE;
    int i = c0 + t;
    bool valid = i < M;
    unsigned long long comp = valid ? g[i] : 0ull;

    unsigned n = valid ? ~(unsigned)comp : 0u;
    int a = (int)(n % A_);
    int pix = (int)(n / A_);
    float4 pre = make_float4(0.f, 0.f, 0.f, 0.f);
    if (valid) pre = ball[(size_t)b * N_ + a * HW_ + pix];

    unsigned key16 = (unsigned)(comp >> 48);
    int f = (key16 >= 32768u) ? (int)(key16 - 32768u) : 0;
    int bs = 0, be = 0;
    if (valid) {
        bs = (f < 32767) ? min((int)S16[f + 1], M) : 0;
        be = min((int)S16[f], M);
    }
    if (t == 0) {
        unsigned kf = (unsigned)(g[c0] >> 48);
        int bf = (kf >= 32768u) ? (int)(kf - 32768u) : 0;
        int last = min(c0 + 255, M - 1);
        unsigned kl = (unsigned)(g[last] >> 48);
        int bl = (kl >= 32768u) ? (int)(kl - 32768u) : 0;
        s_rs = (bf < 32767) ? min((int)S16[bf + 1], M) : 0;
        s_re = min((int)S16[bl], M);
    }
    __syncthreads();
    int rs = s_rs, re = s_re;
    int cgt = 0;
    for (int tb = rs; tb < re; tb += RTILE) {
        int navail = min(RTILE, re - tb);
        __syncthreads();
        for (int j = t; j < navail; j += 256) tile[j] = g[tb + j];
        __syncthreads();
        if (valid) {
            int lo = max(bs, tb) - tb;
            int hi = min(be, tb + navail) - tb;
            int a0 = 0, a1 = 0, a2 = 0, a3 = 0, a4 = 0, a5 = 0, a6 = 0, a7 = 0;
            int j = lo;
            for (; j + 8 <= hi; j += 8) {
                unsigned long long v0 = tile[j + 0];
                unsigned long long v1 = tile[j + 1];
                unsigned long long v2 = tile[j + 2];
                unsigned long long v3 = tile[j + 3];
                unsigned long long v4 = tile[j + 4];
                unsigned long long v5 = tile[j + 5];
                unsigned long long v6 = tile[j + 6];
                unsigned long long v7 = tile[j + 7];
                a0 += (v0 > comp); a1 += (v1 > comp); a2 += (v2 > comp); a3 += (v3 > comp);
                a4 += (v4 > comp); a5 += (v5 > comp); a6 += (v6 > comp); a7 += (v7 > comp);
            }
            for (; j < hi; ++j) cgt += (tile[j] > comp);
            cgt += (a0 + a1 + a2 + a3) + (a4 + a5 + a6 + a7);
        }
    }
    if (!valid) return;
    int rank = bs + cgt;
    if (rank >= PRE_TOP) return;
    boxes[(size_t)b * PRE_TOP + rank] = pre;
}

// NMS: R12 measured-best (4 barriers, t0-serial walk, append phase),
// float4-packed LDS, hoisted lane-own box, ballot-aggregated intra atomics.
__global__ void __launch_bounds__(1024) nms_k(const float4* __restrict__ boxes,
                                              float* __restrict__ out) {
    __shared__ float4 kbox[POST_TOP];
    __shared__ float  karea[POST_TOP];
    __shared__ float4 gbox4[64];
    __shared__ float  gar[64];
    __shared__ unsigned extw[2];
    __shared__ unsigned intraw[128];   // row jj: bits ll that jj suppresses
    __shared__ unsigned long long s_keep;
    __shared__ int s_base, s_kc, s_done;
    int b = blockIdx.x, t = threadIdx.x;
    int lane = t & 63, w = t >> 6;
    if (t == 0) { s_kc = 0; s_done = 0; }
    const float4* bb = boxes + (size_t)b * PRE_TOP;
    const int ngroups = (PRE_TOP + 63) / 64;   // 94

    float4 vcur = make_float4(0.f, 0.f, 0.f, 0.f);
    if (t < 64) vcur = bb[t];                 // prefetch group 0

    for (int g = 0; g < ngroups; ++g) {
        __syncthreads();                       // prev append + s_kc visible
        if (s_done) break;
        int gbase = g * 64;
        int gsz = min(64, PRE_TOP - gbase);
        if (t < gsz) {
            gbox4[t] = vcur;
            gar[t] = __fmul_rn(vcur.z - vcur.x + 1.0f, vcur.w - vcur.y + 1.0f);
        }
        if (t < 64) {                          // prefetch next group under this compute
            int nidx = min(gbase + 64 + t, PRE_TOP - 1);
            vcur = bb[nidx];
        }
        if (t < 2) extw[t] = 0u;
        if (t < 128) intraw[t] = 0u;
        __syncthreads();

        int kc = s_kc;
        // ext phase: 16 threads per candidate vs kept list (packed reads: 2 LDS/iter)
        {
            int j = t >> 4, sub = t & 15;
            if (j < gsz) {
                float4 cb4 = gbox4[j];          // 16-lane broadcast
                float car = gar[j];
                bool any = false;
                for (int kk = sub; kk < kc && !any; kk += 16) {
                    float4 kb = kbox[kk];
                    float ka = karea[kk];
                    any = sup_test(kb.x, kb.y, kb.z, kb.w, ka,
                                   cb4.x, cb4.y, cb4.z, cb4.w, car);
                }
                if (any) atomicOr(&extw[j >> 5], 1u << (j & 31));
            }
        }
        // intra phase: lane = ll (own box in regs); wave w covers jj in
        // {w, w+16, w+32, w+48} (wave-uniform broadcast); ballot-aggregated write.
        {
            float4 mb = gbox4[lane];            // stride-1 b128, conflict-free
            float mar = gar[lane];
#pragma unroll
            for (int it = 0; it < 4; ++it) {
                int jj = w + it * 16;
                float4 bj = gbox4[jj];          // wave-uniform broadcast
                float baj = gar[jj];
                bool sup = (jj < lane) && (lane < gsz) && (jj < gsz) &&
                           sup_test(bj.x, bj.y, bj.z, bj.w, baj,
                                    mb.x, mb.y, mb.z, mb.w, mar);
                unsigned long long m = __ballot(sup);
                if (lane == 0 && (unsigned)m) atomicOr(&intraw[2 * jj], (unsigned)m);
                if (lane == 1 && (unsigned)(m >> 32))
                    atomicOr(&intraw[2 * jj + 1], (unsigned)(m >> 32));
            }
        }
        __syncthreads();

        if (t == 0) {
            unsigned long long ext64 = (unsigned long long)extw[0] |
                                       ((unsigned long long)extw[1] << 32);
            unsigned long long validm = (gsz >= 64) ? ~0ull : ((1ull << gsz) - 1ull);
            unsigned long long alive = (~ext64) & validm;
            unsigned long long keep = 0ull;
            int kcc = s_kc;
            s_base = kcc;
            while (alive && kcc < POST_TOP) {
                int j = __ffsll((long long)alive) - 1;
                keep |= (1ull << j);
                ++kcc;
                unsigned long long row = (unsigned long long)intraw[2 * j] |
                                         ((unsigned long long)intraw[2 * j + 1] << 32);
                alive &= ~row;
                alive &= ~(1ull << j);
            }
            s_keep = keep;
            s_kc = kcc;
            if (kcc >= POST_TOP) s_done = 1;
        }
        __syncthreads();

        if (t < gsz && ((s_keep >> t) & 1ull)) {
            int rank = __popcll(s_keep & ((1ull << t) - 1ull));
            int slot = s_base + rank;
            float4 mb = gbox4[t];
            kbox[slot] = mb;
            karea[slot] = gar[t];
            float* o = out + (size_t)(b * POST_TOP + slot) * 5;
            o[0] = (float)b; o[1] = mb.x; o[2] = mb.y; o[3] = mb.z; o[4] = mb.w;
        }
    }
    __syncthreads();
    for (int sl = s_kc + t; sl < POST_TOP; sl += 1024) {
        float* o = out + (size_t)(b * POST_TOP + sl) * 5;
        o[0] = (float)b; o[1] = 0.f; o[2] = 0.f; o[3] = 0.f; o[4] = 0.f;
    }
}

// ---------- launch ----------

extern "C" void kernel_launch(void* const* d_in, const int* in_sizes, int n_in,
                              void* d_out, int out_size, void* d_ws, size_t ws_size,
                              hipStream_t stream) {
    const float* scores  = (const float*)d_in[0];   // (8, 18, 152, 152)
    const float* deltas  = (const float*)d_in[1];   // (8, 36, 152, 152)
    const float* im_info = (const float*)d_in[2];   // (8, 3)
    const float* anchors = (const float*)d_in[3];   // (9, 4)
    float* out = (float*)d_out;                     // (8, 300, 5)

    unsigned*           hist    = (unsigned*)((char*)d_ws + OFF_HIST);
    unsigned*           cnt     = (unsigned*)((char*)d_ws + OFF_CNT);
    uint2*              cand    = (uint2*)((char*)d_ws + OFF_CAND);
    unsigned long long* grouped = (unsigned long long*)((char*)d_ws + OFF_GROUP);
    float4*             boxes   = (float4*)((char*)d_ws + OFF_BOXES);
    float4*             ball    = (float4*)((char*)d_ws + OFF_BALL);
    unsigned*           done    = cnt + 240;        // inside the zeroed cnt region
    unsigned*           bucketT = cnt + 248;

    init_k<<<DEC_BLKS + ZERO_BLKS, 256, 0, stream>>>(deltas, anchors, im_info, ball,
                                                     (unsigned*)d_ws,
                                                     (unsigned*)((char*)d_ws + OFF_BOXES),
                                                     DEC_BLKS);
    hist_scan_k<<<dim3(64, B_), 256, 0, stream>>>(scores, hist, done, bucketT);
    compact_k<<<dim3(64, B_), 256, 0, stream>>>(scores, bucketT, cnt, cand);
    finesort_k<<<B_, 1024, 0, stream>>>(cnt, cand, grouped);
    rank_k<<<dim3(32, B_), 256, 0, stream>>>(cnt, grouped, (const ushort*)cand, ball, boxes);
    nms_k<<<B_, 1024, 0, stream>>>(boxes, out);
}

// Round 18
// 93.673 us; speedup vs baseline: 1.5640x; 1.2949x over previous
//
#include <hip/hip_runtime.h>
#include <stdint.h>

#define H_ 152
#define W_ 152
#define A_ 9
#define HW_ (H_ * W_)          // 23104
#define N_ (HW_ * A_)          // 207936
#define B_ 8
#define PRE_TOP 6000
#define POST_TOP 300
#define NBUCK 4096
#define NFINE 32768
#define CAND_CAP 8192
#define NMS_TH 0.7f
#define CNT_STRIDE 32          // pad per-batch counters to 128 B
#define RTILE 512
#define DEC_PIXBLK 91          // ceil(23104/256)
#define DEC_BLKS (72 * DEC_PIXBLK)   // 6552
#define ZERO_BLKS 128

// workspace byte offsets
#define OFF_HIST    0                                   // 8*4096*4 = 131072
#define OFF_SSUF    131072                              // (unused, kept for layout)
#define OFF_CNT     262144                              // 8*32*4   = 1024
#define OFF_CAND    263168                              // 8*8192*8 = 524288  (reused as S16 u16[32768]/batch)
#define OFF_GROUP   787456                              // 8*8192*8 = 524288
#define OFF_BOXES   1311744                             // 8*6000*16= 768000
#define OFF_BALL    2079744                             // 8*207936*16 = 26615808
#define WS_NEED     (2079744ull + 26615808ull)          // 28695552

// ---------- helpers ----------

__device__ __forceinline__ unsigned fkey(float f) {
    unsigned u = __float_as_uint(f);
    return (u & 0x80000000u) ? ~u : (u | 0x80000000u);   // monotonic float->u32
}

__device__ __forceinline__ bool sup_test(float ax1, float ay1, float ax2, float ay2, float aar,
                                         float bx1, float by1, float bx2, float by2, float bar) {
    float xx1 = fmaxf(ax1, bx1);
    float yy1 = fmaxf(ay1, by1);
    float xx2 = fminf(ax2, bx2);
    float yy2 = fminf(ay2, by2);
    float iw = fmaxf(xx2 - xx1 + 1.0f, 0.0f);
    float ih = fmaxf(yy2 - yy1 + 1.0f, 0.0f);
    float inter = __fmul_rn(iw, ih);
    float iou = inter / (aar + bar - inter);
    return iou > NMS_TH;
}

// decode one box, op-order identical to reference/numpy
__device__ __forceinline__ float4 decode_box(float an0, float an1, float an2, float an3,
                                             float sx, float sy,
                                             float dx, float dy, float dw, float dh,
                                             float wmax, float hmax) {
    float ax1 = an0 + sx;
    float ay1 = an1 + sy;
    float ax2 = an2 + sx;
    float ay2 = an3 + sy;
    float ww = ax2 - ax1 + 1.0f;
    float hh = ay2 - ay1 + 1.0f;
    float ctx = ax1 + 0.5f * ww;
    float cty = ay1 + 0.5f * hh;
    float pcx = __fadd_rn(__fmul_rn(dx, ww), ctx);   // no FMA contraction (match np)
    float pcy = __fadd_rn(__fmul_rn(dy, hh), cty);
    float pw = __fmul_rn(expf(dw), ww);
    float ph = __fmul_rn(expf(dh), hh);
    float x1 = pcx - 0.5f * pw;
    float y1 = pcy - 0.5f * ph;
    float x2 = pcx + 0.5f * pw;
    float y2 = pcy + 0.5f * ph;
    x1 = fminf(fmaxf(x1, 0.0f), wmax);
    y1 = fminf(fmaxf(y1, 0.0f), hmax);
    x2 = fminf(fmaxf(x2, 0.0f), wmax);
    y2 = fminf(fmaxf(y2, 0.0f), hmax);
    return make_float4(x1, y1, x2, y2);
}

// ---------- kernels ----------

// fused: decode all boxes (blocks 0..DEC_BLKS-1) + zero scratch (last ZERO_BLKS blocks)
__global__ void init_k(const float* __restrict__ deltas,
                       const float* __restrict__ anchors,
                       const float* __restrict__ im_info,
                       float4* __restrict__ ball,
                       unsigned* __restrict__ zbase, unsigned* __restrict__ zboxes,
                       int nDecBlks) {
    int bid = blockIdx.x;
    if (bid < nDecBlks) {
        int ba = bid / DEC_PIXBLK;
        int b = ba / A_, a = ba - (ba / A_) * A_;
        int pix = (bid % DEC_PIXBLK) * 256 + threadIdx.x;
        if (pix >= HW_) return;
        const float* db = deltas + ((size_t)b * 36 + 4 * a) * HW_;
        float dx = db[pix];
        float dy = db[pix + HW_];
        float dw = db[pix + 2 * HW_];
        float dh = db[pix + 3 * HW_];
        float an0 = anchors[a * 4 + 0];
        float an1 = anchors[a * 4 + 1];
        float an2 = anchors[a * 4 + 2];
        float an3 = anchors[a * 4 + 3];
        float hmax = im_info[b * 3 + 0] - 1.0f;
        float wmax = im_info[b * 3 + 1] - 1.0f;
        int w = pix % W_, h = pix / W_;
        float sx = (float)(w * 16), sy = (float)(h * 16);
        ball[(size_t)b * N_ + a * HW_ + pix] =
            decode_box(an0, an1, an2, an3, sx, sy, dx, dy, dw, dh, wmax, hmax);
    } else {
        const int n1 = 263168 / 4;      // hist + (ssuf pad) + cnt
        const int n2 = 768000 / 4;      // boxes (defensive)
        int i = (bid - nDecBlks) * 256 + (int)threadIdx.x;
        int st = ZERO_BLKS * 256;
        for (int k = i; k < n1 + n2; k += st) {
            if (k < n1) zbase[k] = 0u;
            else zboxes[k - n1] = 0u;
        }
    }
}

__global__ void hist_k(const float* __restrict__ scores, unsigned* __restrict__ hist) {
    __shared__ unsigned lh[NBUCK];
    int b = blockIdx.y;
    for (int i = threadIdx.x; i < NBUCK; i += blockDim.x) lh[i] = 0;
    __syncthreads();
    const float4* sb = (const float4*)(scores + ((size_t)b * 18 + A_) * HW_);
    const int N4 = N_ / 4;                      // 51984
    int stride = gridDim.x * blockDim.x;
    for (int e = blockIdx.x * blockDim.x + threadIdx.x; e < N4; e += stride) {
        float4 v = sb[e];
        atomicAdd(&lh[fkey(v.x) >> 20], 1u);
        atomicAdd(&lh[fkey(v.y) >> 20], 1u);
        atomicAdd(&lh[fkey(v.z) >> 20], 1u);
        atomicAdd(&lh[fkey(v.w) >> 20], 1u);
    }
    __syncthreads();
    for (int i = threadIdx.x; i < NBUCK; i += blockDim.x) {
        unsigned v = lh[i];
        if (v) atomicAdd(&hist[b * NBUCK + i], v);
    }
}

// suffix scan from top bucket; finds the coarse threshold bucket only.
__global__ void scan_k(const unsigned* __restrict__ hist, unsigned* __restrict__ bucketT) {
    __shared__ unsigned ps[1024];
    int b = blockIdx.x, t = threadIdx.x;
    const unsigned* hb = hist + b * NBUCK;
    unsigned c0 = hb[4095 - (4 * t + 0)];
    unsigned c1 = hb[4095 - (4 * t + 1)];
    unsigned c2 = hb[4095 - (4 * t + 2)];
    unsigned c3 = hb[4095 - (4 * t + 3)];
    unsigned local = c0 + c1 + c2 + c3;
    ps[t] = local;
    __syncthreads();
    for (int off = 1; off < 1024; off <<= 1) {
        unsigned v = (t >= off) ? ps[t - off] : 0u;
        __syncthreads();
        ps[t] += v;
        __syncthreads();
    }
    unsigned incl = ps[t], excl = incl - local;
    if (excl < PRE_TOP && incl >= PRE_TOP) {
        unsigned cum = excl;
        unsigned cc[4] = {c0, c1, c2, c3};
#pragma unroll
        for (int k = 0; k < 4; ++k) {
            cum += cc[k];
            if (cum >= PRE_TOP) { bucketT[b] = (unsigned)(4095 - (4 * t + k)); break; }
        }
    }
    if (t == 1023 && ps[1023] < PRE_TOP) bucketT[b] = 0;  // safety: include everything
}

__global__ void compact_k(const float* __restrict__ scores, const unsigned* __restrict__ bucketT,
                          unsigned* __restrict__ cnt, uint2* __restrict__ cand) {
    __shared__ unsigned wtot[4], wbase[4];
    __shared__ unsigned blkbase;
    int b = blockIdx.y;
    const float4* sb = (const float4*)(scores + ((size_t)b * 18 + A_) * HW_);
    unsigned T = bucketT[b];
    int lane = threadIdx.x & 63;
    int wid = threadIdx.x >> 6;
    const int N4 = N_ / 4;
    int stride = gridDim.x * blockDim.x;
    int niters = (N4 + stride - 1) / stride;
    unsigned long long lower = (lane == 63) ? 0x7fffffffffffffffull
                                            : ((1ull << lane) - 1ull);
    for (int it = 0; it < niters; ++it) {
        int e = it * stride + blockIdx.x * (int)blockDim.x + (int)threadIdx.x;
        bool p0 = false, p1 = false, p2 = false, p3 = false;
        unsigned k0 = 0, k1 = 0, k2 = 0, k3 = 0;
        if (e < N4) {
            float4 v = sb[e];
            k0 = fkey(v.x); k1 = fkey(v.y); k2 = fkey(v.z); k3 = fkey(v.w);
            p0 = (k0 >> 20) >= T; p1 = (k1 >> 20) >= T;
            p2 = (k2 >> 20) >= T; p3 = (k3 >> 20) >= T;
        }
        unsigned long long m0 = __ballot(p0), m1 = __ballot(p1);
        unsigned long long m2 = __ballot(p2), m3 = __ballot(p3);
        unsigned t0 = (unsigned)__popcll(m0), t1 = (unsigned)__popcll(m1);
        unsigned t2 = (unsigned)__popcll(m2), t3 = (unsigned)__popcll(m3);
        unsigned wtotal = t0 + t1 + t2 + t3;
        if (lane == 0) wtot[wid] = wtotal;
        __syncthreads();
        if (threadIdx.x == 0) {
            unsigned s0 = wtot[0], s1 = wtot[1], s2 = wtot[2], s3 = wtot[3];
            unsigned tot = s0 + s1 + s2 + s3;
            blkbase = tot ? atomicAdd(&cnt[b * CNT_STRIDE], tot) : 0u;
            wbase[0] = 0; wbase[1] = s0; wbase[2] = s0 + s1; wbase[3] = s0 + s1 + s2;
        }
        __syncthreads();
        if (wtotal) {
            unsigned base = blkbase + wbase[wid];
            unsigned o0 = base + (unsigned)__popcll(m0 & lower);
            unsigned o1 = base + t0 + (unsigned)__popcll(m1 & lower);
            unsigned o2 = base + t0 + t1 + (unsigned)__popcll(m2 & lower);
            unsigned o3 = base + t0 + t1 + t2 + (unsigned)__popcll(m3 & lower);
            uint2* cb = cand + (size_t)b * CAND_CAP;
            int e4 = e * 4;
            if (p0 && o0 < CAND_CAP) {
                int a = (e4 + 0) / HW_, pix = (e4 + 0) - a * HW_;
                cb[o0] = make_uint2(k0, (unsigned)(pix * A_ + a));
            }
            if (p1 && o1 < CAND_CAP) {
                int a = (e4 + 1) / HW_, pix = (e4 + 1) - a * HW_;
                cb[o1] = make_uint2(k1, (unsigned)(pix * A_ + a));
            }
            if (p2 && o2 < CAND_CAP) {
                int a = (e4 + 2) / HW_, pix = (e4 + 2) - a * HW_;
                cb[o2] = make_uint2(k2, (unsigned)(pix * A_ + a));
            }
            if (p3 && o3 < CAND_CAP) {
                int a = (e4 + 3) / HW_, pix = (e4 + 3) - a * HW_;
                cb[o3] = make_uint2(k3, (unsigned)(pix * A_ + a));
            }
        }
    }
}

// Fine (16-bit) counting sort of candidates: histogram -> suffix scan -> scatter.
// Afterwards writes per-fine-bucket END offsets (u16) over the dead cand slice.
__global__ void __launch_bounds__(1024) finesort_k(const unsigned* __restrict__ cnt,
                                                   uint2* __restrict__ cand,
                                                   unsigned long long* __restrict__ grouped) {
    __shared__ unsigned lh[NFINE];     // 128 KiB
    __shared__ unsigned ps[1024];
    int b = blockIdx.x, t = threadIdx.x;
    int M = min((int)cnt[b * CNT_STRIDE], CAND_CAP);
    uint2* cb = cand + (size_t)b * CAND_CAP;
    unsigned long long* g = grouped + (size_t)b * CAND_CAP;
    for (int i = t; i < NFINE; i += 1024) lh[i] = 0u;
    __syncthreads();
    for (int i = t; i < M; i += 1024) {
        unsigned key16 = cb[i].x >> 16;
        unsigned f = (key16 >= 32768u) ? (key16 - 32768u) : 0u;
        atomicAdd(&lh[f], 1u);
    }
    __syncthreads();
    unsigned c[32];
    unsigned local = 0;
#pragma unroll
    for (int k = 0; k < 32; ++k) { c[k] = lh[32767 - (32 * t + k)]; local += c[k]; }
    ps[t] = local;
    __syncthreads();
    for (int off = 1; off < 1024; off <<= 1) {
        unsigned v = (t >= off) ? ps[t - off] : 0u;
        __syncthreads();
        ps[t] += v;
        __syncthreads();
    }
    unsigned run = ps[t] - local;       // elements in all higher-f chunks
    __syncthreads();
#pragma unroll
    for (int k = 0; k < 32; ++k) {      // overwrite lh with S_start[f]
        lh[32767 - (32 * t + k)] = run;
        run += c[k];
    }
    __syncthreads();
    for (int i = t; i < M; i += 1024) {
        uint2 cd = cb[i];
        unsigned key16 = cd.x >> 16;
        unsigned f = (key16 >= 32768u) ? (key16 - 32768u) : 0u;
        unsigned pos = atomicAdd(&lh[f], 1u);
        if (pos < CAND_CAP)
            g[pos] = ((unsigned long long)cd.x << 32) | (unsigned)(~cd.y);
    }
    __syncthreads();
    ushort* S16 = (ushort*)cb;          // cand slice is dead; 32768*2B = 64 KiB fits exactly
    for (int i = t; i < NFINE; i += 1024)
        S16[i] = (ushort)min(lh[i], 65535u);
}

// rank candidate within its FINE bucket (count greater composites), then place its
// (pre-decoded) box into boxes[b][rank].
__global__ void __launch_bounds__(256) rank_k(const unsigned* __restrict__ cnt,
                                              const unsigned long long* __restrict__ grouped,
                                              const ushort* __restrict__ S16all,
                                              const float4* __restrict__ ball,
                                              float4* __restrict__ boxes) {
    __shared__ unsigned long long tile[RTILE];
    __shared__ int s_rs, s_re;
    int b = blockIdx.y, t = threadIdx.x;
    int M = min((int)cnt[b * CNT_STRIDE], CAND_CAP);
    int c0 = blockIdx.x * 256;
    if (c0 >= M) return;
    const unsigned long long* g = grouped + (size_t)b * CAND_CAP;
    const ushort* S16 = S16all + (size_t)b * NFINE;
    int i = c0 + t;
    bool valid = i < M;
    unsigned long long comp = valid ? g[i] : 0ull;

    unsigned n = valid ? ~(unsigned)comp : 0u;
    int a = (int)(n % A_);
    int pix = (int)(n / A_);
    float4 pre = make_float4(0.f, 0.f, 0.f, 0.f);
    if (valid) pre = ball[(size_t)b * N_ + a * HW_ + pix];

    unsigned key16 = (unsigned)(comp >> 48);
    int f = (key16 >= 32768u) ? (int)(key16 - 32768u) : 0;
    int bs = 0, be = 0;
    if (valid) {
        bs = (f < 32767) ? min((int)S16[f + 1], M) : 0;
        be = min((int)S16[f], M);
    }
    if (t == 0) {
        unsigned kf = (unsigned)(g[c0] >> 48);
        int bf = (kf >= 32768u) ? (int)(kf - 32768u) : 0;
        int last = min(c0 + 255, M - 1);
        unsigned kl = (unsigned)(g[last] >> 48);
        int bl = (kl >= 32768u) ? (int)(kl - 32768u) : 0;
        s_rs = (bf < 32767) ? min((int)S16[bf + 1], M) : 0;
        s_re = min((int)S16[bl], M);
    }
    __syncthreads();
    int rs = s_rs, re = s_re;
    int cgt = 0;
    for (int tb = rs; tb < re; tb += RTILE) {
        int navail = min(RTILE, re - tb);
        __syncthreads();
        for (int j = t; j < navail; j += 256) tile[j] = g[tb + j];
        __syncthreads();
        if (valid) {
            int lo = max(bs, tb) - tb;
            int hi = min(be, tb + navail) - tb;
            int a0 = 0, a1 = 0, a2 = 0, a3 = 0, a4 = 0, a5 = 0, a6 = 0, a7 = 0;
            int j = lo;
            for (; j + 8 <= hi; j += 8) {
                unsigned long long v0 = tile[j + 0];
                unsigned long long v1 = tile[j + 1];
                unsigned long long v2 = tile[j + 2];
                unsigned long long v3 = tile[j + 3];
                unsigned long long v4 = tile[j + 4];
                unsigned long long v5 = tile[j + 5];
                unsigned long long v6 = tile[j + 6];
                unsigned long long v7 = tile[j + 7];
                a0 += (v0 > comp); a1 += (v1 > comp); a2 += (v2 > comp); a3 += (v3 > comp);
                a4 += (v4 > comp); a5 += (v5 > comp); a6 += (v6 > comp); a7 += (v7 > comp);
            }
            for (; j < hi; ++j) cgt += (tile[j] > comp);
            cgt += (a0 + a1 + a2 + a3) + (a4 + a5 + a6 + a7);
        }
    }
    if (!valid) return;
    int rank = bs + cgt;
    if (rank >= PRE_TOP) return;
    boxes[(size_t)b * PRE_TOP + rank] = pre;
}

// NMS: proven skeleton (4 barriers, t0-serial walk, append phase) with
// float4-packed LDS, hoisted lane-own box, ballot-aggregated intra atomics.
__global__ void __launch_bounds__(1024) nms_k(const float4* __restrict__ boxes,
                                              float* __restrict__ out) {
    __shared__ float4 kbox[POST_TOP];
    __shared__ float  karea[POST_TOP];
    __shared__ float4 gbox4[64];
    __shared__ float  gar[64];
    __shared__ unsigned extw[2];
    __shared__ unsigned intraw[128];   // row jj: bits ll that jj suppresses
    __shared__ unsigned long long s_keep;
    __shared__ int s_base, s_kc, s_done;
    int b = blockIdx.x, t = threadIdx.x;
    int lane = t & 63, w = t >> 6;
    if (t == 0) { s_kc = 0; s_done = 0; }
    const float4* bb = boxes + (size_t)b * PRE_TOP;
    const int ngroups = (PRE_TOP + 63) / 64;   // 94

    float4 vcur = make_float4(0.f, 0.f, 0.f, 0.f);
    if (t < 64) vcur = bb[t];                 // prefetch group 0

    for (int g = 0; g < ngroups; ++g) {
        __syncthreads();                       // prev append + s_kc visible
        if (s_done) break;
        int gbase = g * 64;
        int gsz = min(64, PRE_TOP - gbase);
        if (t < gsz) {
            gbox4[t] = vcur;
            gar[t] = __fmul_rn(vcur.z - vcur.x + 1.0f, vcur.w - vcur.y + 1.0f);
        }
        if (t < 64) {                          // prefetch next group under this compute
            int nidx = min(gbase + 64 + t, PRE_TOP - 1);
            vcur = bb[nidx];
        }
        if (t < 2) extw[t] = 0u;
        if (t < 128) intraw[t] = 0u;
        __syncthreads();

        int kc = s_kc;
        // ext phase: 16 threads per candidate vs kept list (packed reads: 2 LDS/iter)
        {
            int j = t >> 4, sub = t & 15;
            if (j < gsz) {
                float4 cb4 = gbox4[j];          // 16-lane broadcast
                float car = gar[j];
                bool any = false;
                for (int kk = sub; kk < kc && !any; kk += 16) {
                    float4 kb = kbox[kk];
                    float ka = karea[kk];
                    any = sup_test(kb.x, kb.y, kb.z, kb.w, ka,
                                   cb4.x, cb4.y, cb4.z, cb4.w, car);
                }
                if (any) atomicOr(&extw[j >> 5], 1u << (j & 31));
            }
        }
        // intra phase: lane = ll (own box in regs, read once); wave w covers
        // jj in {w, w+16, w+32, w+48} (wave-uniform -> broadcast reads);
        // ballot-aggregated mask write (2 atomics per wave-iter).
        {
            float4 mb = gbox4[lane];            // stride-1 b128, conflict-free
            float mar = gar[lane];
#pragma unroll
            for (int it = 0; it < 4; ++it) {
                int jj = w + it * 16;
                float4 bj = gbox4[jj];          // wave-uniform broadcast
                float baj = gar[jj];
                bool sup = (jj < lane) && (lane < gsz) && (jj < gsz) &&
                           sup_test(bj.x, bj.y, bj.z, bj.w, baj,
                                    mb.x, mb.y, mb.z, mb.w, mar);
                unsigned long long m = __ballot(sup);
                if (lane == 0 && (unsigned)m) atomicOr(&intraw[2 * jj], (unsigned)m);
                if (lane == 1 && (unsigned)(m >> 32))
                    atomicOr(&intraw[2 * jj + 1], (unsigned)(m >> 32));
            }
        }
        __syncthreads();

        if (t == 0) {
            unsigned long long ext64 = (unsigned long long)extw[0] |
                                       ((unsigned long long)extw[1] << 32);
            unsigned long long validm = (gsz >= 64) ? ~0ull : ((1ull << gsz) - 1ull);
            unsigned long long alive = (~ext64) & validm;
            unsigned long long keep = 0ull;
            int kcc = s_kc;
            s_base = kcc;
            while (alive && kcc < POST_TOP) {
                int j = __ffsll((long long)alive) - 1;
                keep |= (1ull << j);
                ++kcc;
                unsigned long long row = (unsigned long long)intraw[2 * j] |
                                         ((unsigned long long)intraw[2 * j + 1] << 32);
                alive &= ~row;
                alive &= ~(1ull << j);
            }
            s_keep = keep;
            s_kc = kcc;
            if (kcc >= POST_TOP) s_done = 1;
        }
        __syncthreads();

        if (t < gsz && ((s_keep >> t) & 1ull)) {
            int rank = __popcll(s_keep & ((1ull << t) - 1ull));
            int slot = s_base + rank;
            float4 mb = gbox4[t];
            kbox[slot] = mb;
            karea[slot] = gar[t];
            float* o = out + (size_t)(b * POST_TOP + slot) * 5;
            o[0] = (float)b; o[1] = mb.x; o[2] = mb.y; o[3] = mb.z; o[4] = mb.w;
        }
    }
    __syncthreads();
    for (int sl = s_kc + t; sl < POST_TOP; sl += 1024) {
        float* o = out + (size_t)(b * POST_TOP + sl) * 5;
        o[0] = (float)b; o[1] = 0.f; o[2] = 0.f; o[3] = 0.f; o[4] = 0.f;
    }
}

// ---------- launch ----------

extern "C" void kernel_launch(void* const* d_in, const int* in_sizes, int n_in,
                              void* d_out, int out_size, void* d_ws, size_t ws_size,
                              hipStream_t stream) {
    const float* scores  = (const float*)d_in[0];   // (8, 18, 152, 152)
    const float* deltas  = (const float*)d_in[1];   // (8, 36, 152, 152)
    const float* im_info = (const float*)d_in[2];   // (8, 3)
    const float* anchors = (const float*)d_in[3];   // (9, 4)
    float* out = (float*)d_out;                     // (8, 300, 5)

    unsigned*           hist    = (unsigned*)((char*)d_ws + OFF_HIST);
    unsigned*           cnt     = (unsigned*)((char*)d_ws + OFF_CNT);
    uint2*              cand    = (uint2*)((char*)d_ws + OFF_CAND);
    unsigned long long* grouped = (unsigned long long*)((char*)d_ws + OFF_GROUP);
    float4*             boxes   = (float4*)((char*)d_ws + OFF_BOXES);
    float4*             ball    = (float4*)((char*)d_ws + OFF_BALL);
    unsigned*           bucketT = cnt + B_ * CNT_STRIDE - 8;  // tail of cnt pad, not aliased

    init_k<<<DEC_BLKS + ZERO_BLKS, 256, 0, stream>>>(deltas, anchors, im_info, ball,
                                                     (unsigned*)d_ws,
                                                     (unsigned*)((char*)d_ws + OFF_BOXES),
                                                     DEC_BLKS);
    hist_k<<<dim3(64, B_), 256, 0, stream>>>(scores, hist);
    scan_k<<<B_, 1024, 0, stream>>>(hist, bucketT);
    compact_k<<<dim3(64, B_), 256, 0, stream>>>(scores, bucketT, cnt, cand);
    finesort_k<<<B_, 1024, 0, stream>>>(cnt, cand, grouped);
    rank_k<<<dim3(32, B_), 256, 0, stream>>>(cnt, grouped, (const ushort*)cand, ball, boxes);
    nms_k<<<B_, 1024, 0, stream>>>(boxes, out);
}